// Round 1
// baseline (372.928 us; speedup 1.0000x reference)
//
#include <hip/hip_runtime.h>

// GConvGRU with H=0: only two ChebConvs on X survive.
//   Z  = sigmoid(X@Wz0 + Tx1@Wz1 + Tx2@Wz2 + b_xz + b_hz)
//   Ht = tanh   (X@Wh0 + Tx1@Wh1 + Tx2@Wh2 + b_xh + b_hh)
//   H_new = (1-Z)*Ht
// Tx1 = L_hat@X, Tx2 = 2*L_hat@Tx1 - X, L_hat entries w_off = -w*dinv[s]*dinv[d]
// (LAM=2 => 2/LAM=1, diag = 0).

#define N_NODES 50000
#define E_EDGES 800000
#define NC 64

// ws layout (4-byte element offsets)
#define OFF_DEG      0           // float[50176]  deg -> dinv in place
#define OFF_CNT      50176       // int[50176]
#define OFF_ROWSTART 100352      // int[50176] (uses N+1)
#define OFF_CURSOR   150528      // int[50176]
#define OFF_EXCL     200704      // int[50176]
#define OFF_BSUM     250880      // int[256]
#define OFF_COL      251136      // int[800000]
#define OFF_VAL      1051136     // float[800000]
#define OFF_TX1      1851136     // float[3200000]
#define OFF_TX2      5051136     // float[3200000]

__global__ void k_deg_cnt(const int* __restrict__ ei, const float* __restrict__ ew,
                          float* __restrict__ deg, int* __restrict__ cnt) {
    int e = blockIdx.x * blockDim.x + threadIdx.x;
    if (e >= E_EDGES) return;
    int s = ei[e];
    int d = ei[E_EDGES + e];
    atomicAdd(&deg[s], ew[e]);
    atomicAdd(&cnt[d], 1);
}

__global__ void k_dinv(float* __restrict__ deg) {
    int i = blockIdx.x * blockDim.x + threadIdx.x;
    if (i >= N_NODES) return;
    float dg = deg[i];
    deg[i] = dg > 0.f ? rsqrtf(dg) : 0.f;
}

// hierarchical exclusive scan of cnt -> row_start (and cursor copy)
__global__ void k_scanA(const int* __restrict__ cnt, int* __restrict__ excl,
                        int* __restrict__ bsum) {
    __shared__ int s[256];
    int tid = threadIdx.x;
    int i = blockIdx.x * 256 + tid;
    int v = (i < N_NODES) ? cnt[i] : 0;
    s[tid] = v; __syncthreads();
    for (int off = 1; off < 256; off <<= 1) {
        int t = (tid >= off) ? s[tid - off] : 0;
        __syncthreads();
        s[tid] += t;
        __syncthreads();
    }
    if (i < N_NODES) excl[i] = s[tid] - v;
    if (tid == 255) bsum[blockIdx.x] = s[255];
}

__global__ void k_scanB(int* __restrict__ bsum, int nb) {
    __shared__ int s[256];
    int tid = threadIdx.x;
    int v = (tid < nb) ? bsum[tid] : 0;
    s[tid] = v; __syncthreads();
    for (int off = 1; off < 256; off <<= 1) {
        int t = (tid >= off) ? s[tid - off] : 0;
        __syncthreads();
        s[tid] += t;
        __syncthreads();
    }
    if (tid < nb) bsum[tid] = s[tid] - v;   // exclusive
}

__global__ void k_scanC(const int* __restrict__ excl, const int* __restrict__ bsum,
                        int* __restrict__ row_start, int* __restrict__ cursor) {
    int i = blockIdx.x * 256 + threadIdx.x;
    if (i < N_NODES) {
        int r = excl[i] + bsum[i >> 8];
        row_start[i] = r;
        cursor[i] = r;
    }
    if (i == 0) row_start[N_NODES] = E_EDGES;
}

__global__ void k_scatter(const int* __restrict__ ei, const float* __restrict__ ew,
                          const float* __restrict__ dinv, int* __restrict__ cursor,
                          int* __restrict__ col, float* __restrict__ val) {
    int e = blockIdx.x * blockDim.x + threadIdx.x;
    if (e >= E_EDGES) return;
    int s = ei[e];
    int d = ei[E_EDGES + e];
    float wv = -ew[e] * dinv[s] * dinv[d];     // *(2/LAM)=1
    int pos = atomicAdd(&cursor[d], 1);
    col[pos] = s;
    val[pos] = wv;
}

// Pull-mode SpMM: one wave per row, lane = channel.
// out[row] = SCALE*sum_j val[j]*xin[col[j]]  (+ SUB ? -xprev[row] : 0)
template<int SCALE, int SUB>
__global__ __launch_bounds__(256) void k_spmm(
        const int* __restrict__ row_start, const int* __restrict__ col,
        const float* __restrict__ val, const float* __restrict__ xin,
        const float* __restrict__ xprev, float* __restrict__ out) {
    int wid = (blockIdx.x * blockDim.x + threadIdx.x) >> 6;
    int lane = threadIdx.x & 63;
    if (wid >= N_NODES) return;
    int start = row_start[wid];
    int end   = row_start[wid + 1];
    float acc = 0.f;
    for (int j = start; j < end; ++j) {
        int s = col[j];
        float wv = val[j];
        acc = fmaf(wv, xin[(size_t)s * NC + lane], acc);
    }
    float r = (float)SCALE * acc;
    if (SUB) r -= xprev[(size_t)wid * NC + lane];
    out[(size_t)wid * NC + lane] = r;
}

// Fused 3-term GEMM for both gates + GRU pointwise.
// 64 nodes per block, 256 threads: thread = (o = tid&63, nq = tid>>6),
// each thread accumulates 16 nodes (nl*4 + nq) for output channel o.
__global__ __launch_bounds__(256) void k_gru(
        const float* __restrict__ X, const float* __restrict__ Tx1,
        const float* __restrict__ Tx2,
        const float* __restrict__ Wxz, const float* __restrict__ Wxh,
        const float* __restrict__ bxz, const float* __restrict__ bhz,
        const float* __restrict__ bxh, const float* __restrict__ bhh,
        float* __restrict__ out) {
    __shared__ float sWz[64][64];
    __shared__ float sWh[64][64];
    __shared__ float sIn[64][64];
    int tid = threadIdx.x;
    int o = tid & 63;
    int nq = tid >> 6;
    int node0 = blockIdx.x * 64;

    float accz[16], acch[16];
    #pragma unroll
    for (int i = 0; i < 16; ++i) { accz[i] = 0.f; acch[i] = 0.f; }

    const float* ins[3] = {X, Tx1, Tx2};
    for (int k = 0; k < 3; ++k) {
        __syncthreads();
        #pragma unroll
        for (int r = 0; r < 16; ++r) {
            int idx = r * 256 + tid;
            ((float*)sWz)[idx] = Wxz[k * 4096 + idx];
            ((float*)sWh)[idx] = Wxh[k * 4096 + idx];
        }
        const float* ip = ins[k];
        #pragma unroll
        for (int r = 0; r < 16; ++r) {
            int idx = r * 256 + tid;
            int node = node0 + (idx >> 6);
            ((float*)sIn)[idx] = (node < N_NODES) ? ip[(size_t)node * 64 + (idx & 63)] : 0.f;
        }
        __syncthreads();
        for (int c = 0; c < 64; ++c) {
            float wz = sWz[c][o];
            float wh = sWh[c][o];
            #pragma unroll
            for (int nl = 0; nl < 16; ++nl) {
                float xv = sIn[nl * 4 + nq][c];
                accz[nl] = fmaf(xv, wz, accz[nl]);
                acch[nl] = fmaf(xv, wh, acch[nl]);
            }
        }
    }

    float bz = bxz[o] + bhz[o];
    float bh = bxh[o] + bhh[o];
    #pragma unroll
    for (int nl = 0; nl < 16; ++nl) {
        int node = node0 + nl * 4 + nq;
        if (node < N_NODES) {
            float z = accz[nl] + bz;
            float h = acch[nl] + bh;
            float sig = 1.f / (1.f + __expf(-z));
            float e2 = __expf(-2.f * h);
            float th = (1.f - e2) / (1.f + e2);
            out[(size_t)node * 64 + o] = (1.f - sig) * th;
        }
    }
}

extern "C" void kernel_launch(void* const* d_in, const int* in_sizes, int n_in,
                              void* d_out, int out_size, void* d_ws, size_t ws_size,
                              hipStream_t stream) {
    const float* X   = (const float*)d_in[0];
    const int*   ei  = (const int*)d_in[1];      // [2, E] int
    const float* ew  = (const float*)d_in[2];
    const float* Wxz = (const float*)d_in[3];    // [3,64,64]
    const float* Wxh = (const float*)d_in[7];
    const float* bxz = (const float*)d_in[9];
    const float* bhz = (const float*)d_in[10];
    const float* bxh = (const float*)d_in[13];
    const float* bhh = (const float*)d_in[14];
    float* out = (float*)d_out;

    float* ws_f = (float*)d_ws;
    int*   ws_i = (int*)d_ws;

    float* deg      = ws_f + OFF_DEG;
    int*   cnt      = ws_i + OFF_CNT;
    int*   rowstart = ws_i + OFF_ROWSTART;
    int*   cursor   = ws_i + OFF_CURSOR;
    int*   excl     = ws_i + OFF_EXCL;
    int*   bsum     = ws_i + OFF_BSUM;
    int*   col      = ws_i + OFF_COL;
    float* val      = ws_f + OFF_VAL;
    float* tx1      = ws_f + OFF_TX1;
    float* tx2      = ws_f + OFF_TX2;

    // zero deg + cnt
    hipMemsetAsync(d_ws, 0, (size_t)(OFF_ROWSTART) * 4, stream);

    const int TB = 256;
    int eb = (E_EDGES + TB - 1) / TB;           // 3125
    int nb = (N_NODES + TB - 1) / TB;           // 196

    k_deg_cnt<<<eb, TB, 0, stream>>>(ei, ew, deg, cnt);
    k_dinv<<<nb, TB, 0, stream>>>(deg);
    k_scanA<<<nb, TB, 0, stream>>>(cnt, excl, bsum);
    k_scanB<<<1, TB, 0, stream>>>(bsum, nb);
    k_scanC<<<nb, TB, 0, stream>>>(excl, bsum, rowstart, cursor);
    k_scatter<<<eb, TB, 0, stream>>>(ei, ew, deg, cursor, col, val);

    // Tx1 = L_hat @ X
    k_spmm<1, 0><<<(N_NODES + 3) / 4, TB, 0, stream>>>(rowstart, col, val, X, X, tx1);
    // Tx2 = 2 * L_hat @ Tx1 - X
    k_spmm<2, 1><<<(N_NODES + 3) / 4, TB, 0, stream>>>(rowstart, col, val, tx1, X, tx2);

    k_gru<<<(N_NODES + 63) / 64, TB, 0, stream>>>(X, tx1, tx2, Wxz, Wxh,
                                                  bxz, bhz, bxh, bhh, out);
}

// Round 2
// 273.934 us; speedup vs baseline: 1.3614x; 1.3614x over previous
//
#include <hip/hip_runtime.h>

// GConvGRU with H=0: only two ChebConvs on X survive.
//   Z  = sigmoid(X@Wz0 + Tx1@Wz1 + Tx2@Wz2 + b_xz + b_hz)
//   Ht = tanh   (X@Wh0 + Tx1@Wh1 + Tx2@Wh2 + b_xh + b_hh)
//   H_new = (1-Z)*Ht
// Tx1 = L_hat@X, Tx2 = 2*L_hat@Tx1 - X, L_hat entries w_off = -w*dinv[s]*dinv[d]

#define N_NODES 50000
#define E_EDGES 800000
#define NC 64

// ws layout (4-byte element offsets)
#define OFF_DEG      0           // float[50176]
#define OFF_CNT      50176      // int[50176]
#define OFF_ROWSTART 100352     // int[50432]
#define OFF_CURSOR   150784     // int[50176]
#define OFF_EXCL     200960     // int[50176]
#define OFF_BSUM     251136     // int[256]
#define OFF_CV       251392     // long long[800000] (packed col|val), 8B aligned
#define OFF_TX1      1851392    // float[3200000]
#define OFF_TX2      5051392    // float[3200000]

__global__ void k_deg_cnt(const int* __restrict__ ei, const float* __restrict__ ew,
                          float* __restrict__ deg, int* __restrict__ cnt) {
    int e = blockIdx.x * blockDim.x + threadIdx.x;
    if (e >= E_EDGES) return;
    int s = ei[e];
    int d = ei[E_EDGES + e];
    atomicAdd(&deg[s], ew[e]);
    atomicAdd(&cnt[d], 1);
}

__global__ void k_dinv(float* __restrict__ deg) {
    int i = blockIdx.x * blockDim.x + threadIdx.x;
    if (i >= N_NODES) return;
    float dg = deg[i];
    deg[i] = dg > 0.f ? rsqrtf(dg) : 0.f;
}

__global__ void k_scanA(const int* __restrict__ cnt, int* __restrict__ excl,
                        int* __restrict__ bsum) {
    __shared__ int s[256];
    int tid = threadIdx.x;
    int i = blockIdx.x * 256 + tid;
    int v = (i < N_NODES) ? cnt[i] : 0;
    s[tid] = v; __syncthreads();
    for (int off = 1; off < 256; off <<= 1) {
        int t = (tid >= off) ? s[tid - off] : 0;
        __syncthreads();
        s[tid] += t;
        __syncthreads();
    }
    if (i < N_NODES) excl[i] = s[tid] - v;
    if (tid == 255) bsum[blockIdx.x] = s[255];
}

__global__ void k_scanB(int* __restrict__ bsum, int nb) {
    __shared__ int s[256];
    int tid = threadIdx.x;
    int v = (tid < nb) ? bsum[tid] : 0;
    s[tid] = v; __syncthreads();
    for (int off = 1; off < 256; off <<= 1) {
        int t = (tid >= off) ? s[tid - off] : 0;
        __syncthreads();
        s[tid] += t;
        __syncthreads();
    }
    if (tid < nb) bsum[tid] = s[tid] - v;   // exclusive
}

__global__ void k_scanC(const int* __restrict__ excl, const int* __restrict__ bsum,
                        int* __restrict__ row_start, int* __restrict__ cursor) {
    int i = blockIdx.x * 256 + threadIdx.x;
    if (i < N_NODES) {
        int r = excl[i] + bsum[i >> 8];
        row_start[i] = r;
        cursor[i] = r;
    }
    if (i == 0) row_start[N_NODES] = E_EDGES;
}

__global__ void k_scatter(const int* __restrict__ ei, const float* __restrict__ ew,
                          const float* __restrict__ dinv, int* __restrict__ cursor,
                          long long* __restrict__ cv) {
    int e = blockIdx.x * blockDim.x + threadIdx.x;
    if (e >= E_EDGES) return;
    int s = ei[e];
    int d = ei[E_EDGES + e];
    float wv = -ew[e] * dinv[s] * dinv[d];
    int pos = atomicAdd(&cursor[d], 1);
    cv[pos] = ((long long)__float_as_int(wv) << 32) | (unsigned int)s;
}

// Pull-mode SpMM: one wave per row, lane = channel.
template<int SCALE, int SUB>
__global__ __launch_bounds__(256) void k_spmm(
        const int* __restrict__ row_start, const long long* __restrict__ cv,
        const float* __restrict__ xin, const float* __restrict__ xprev,
        float* __restrict__ out) {
    int wid = (blockIdx.x << 2) + (threadIdx.x >> 6);
    int lane = threadIdx.x & 63;
    if (wid >= N_NODES) return;
    int start = row_start[wid];
    int end   = row_start[wid + 1];
    float acc = 0.f;
    #pragma unroll 4
    for (int j = start; j < end; ++j) {
        long long p = cv[j];
        int s = (int)(p & 0xffffffffLL);
        float wv = __int_as_float((int)(p >> 32));
        acc = fmaf(wv, xin[(size_t)s * NC + lane], acc);
    }
    float r = (float)SCALE * acc;
    if (SUB) r -= xprev[(size_t)wid * NC + lane];
    out[(size_t)wid * NC + lane] = r;
}

// Fused 3-term GEMM for both gates + GRU pointwise.
// 64 nodes/block, 256 threads: thread = (o = tid&63, nq = tid>>6),
// each thread accumulates 16 nodes (nl*4 + nq) for output channel o.
// Inputs staged as float4 to cut LDS instruction count 3x.
__global__ __launch_bounds__(256) void k_gru(
        const float* __restrict__ X, const float* __restrict__ Tx1,
        const float* __restrict__ Tx2,
        const float* __restrict__ Wxz, const float* __restrict__ Wxh,
        const float* __restrict__ bxz, const float* __restrict__ bhz,
        const float* __restrict__ bxh, const float* __restrict__ bhh,
        float* __restrict__ out) {
    __shared__ float sWz[64][64];    // [c][o]
    __shared__ float sWh[64][64];
    __shared__ float4 sIn[64][16];   // [node_local][c4]
    int tid = threadIdx.x;
    int o = tid & 63;
    int nq = tid >> 6;
    int node0 = blockIdx.x * 64;

    float accz[16], acch[16];
    #pragma unroll
    for (int i = 0; i < 16; ++i) { accz[i] = 0.f; acch[i] = 0.f; }

    const float* ins[3] = {X, Tx1, Tx2};
    #pragma unroll 1
    for (int k = 0; k < 3; ++k) {
        __syncthreads();
        #pragma unroll
        for (int r = 0; r < 16; ++r) {
            int idx = r * 256 + tid;
            ((float*)sWz)[idx] = Wxz[k * 4096 + idx];
            ((float*)sWh)[idx] = Wxh[k * 4096 + idx];
        }
        const float* ip = ins[k];
        #pragma unroll
        for (int r = 0; r < 4; ++r) {
            int fidx = r * 256 + tid;        // 0..1023
            int node = fidx >> 4;
            int c4 = fidx & 15;
            int gn = node0 + node;
            float4 v = make_float4(0.f, 0.f, 0.f, 0.f);
            if (gn < N_NODES) v = *(const float4*)&ip[(size_t)gn * 64 + c4 * 4];
            sIn[node][c4] = v;
        }
        __syncthreads();
        #pragma unroll 4
        for (int c4 = 0; c4 < 16; ++c4) {
            float wz0 = sWz[c4 * 4 + 0][o];
            float wz1 = sWz[c4 * 4 + 1][o];
            float wz2 = sWz[c4 * 4 + 2][o];
            float wz3 = sWz[c4 * 4 + 3][o];
            float wh0 = sWh[c4 * 4 + 0][o];
            float wh1 = sWh[c4 * 4 + 1][o];
            float wh2 = sWh[c4 * 4 + 2][o];
            float wh3 = sWh[c4 * 4 + 3][o];
            #pragma unroll
            for (int nl = 0; nl < 16; ++nl) {
                float4 xv = sIn[nl * 4 + nq][c4];
                accz[nl] = fmaf(xv.x, wz0, accz[nl]);
                accz[nl] = fmaf(xv.y, wz1, accz[nl]);
                accz[nl] = fmaf(xv.z, wz2, accz[nl]);
                accz[nl] = fmaf(xv.w, wz3, accz[nl]);
                acch[nl] = fmaf(xv.x, wh0, acch[nl]);
                acch[nl] = fmaf(xv.y, wh1, acch[nl]);
                acch[nl] = fmaf(xv.z, wh2, acch[nl]);
                acch[nl] = fmaf(xv.w, wh3, acch[nl]);
            }
        }
    }

    float bz = bxz[o] + bhz[o];
    float bh = bxh[o] + bhh[o];
    #pragma unroll
    for (int nl = 0; nl < 16; ++nl) {
        int node = node0 + nl * 4 + nq;
        if (node < N_NODES) {
            float z = accz[nl] + bz;
            float h = acch[nl] + bh;
            float sig = 1.f / (1.f + __expf(-z));
            float e2 = __expf(-2.f * h);
            float th = (1.f - e2) / (1.f + e2);
            out[(size_t)node * 64 + o] = (1.f - sig) * th;
        }
    }
}

extern "C" void kernel_launch(void* const* d_in, const int* in_sizes, int n_in,
                              void* d_out, int out_size, void* d_ws, size_t ws_size,
                              hipStream_t stream) {
    const float* X   = (const float*)d_in[0];
    const int*   ei  = (const int*)d_in[1];
    const float* ew  = (const float*)d_in[2];
    const float* Wxz = (const float*)d_in[3];
    const float* Wxh = (const float*)d_in[7];
    const float* bxz = (const float*)d_in[9];
    const float* bhz = (const float*)d_in[10];
    const float* bxh = (const float*)d_in[13];
    const float* bhh = (const float*)d_in[14];
    float* out = (float*)d_out;

    float* ws_f = (float*)d_ws;
    int*   ws_i = (int*)d_ws;

    float*     deg      = ws_f + OFF_DEG;
    int*       cnt      = ws_i + OFF_CNT;
    int*       rowstart = ws_i + OFF_ROWSTART;
    int*       cursor   = ws_i + OFF_CURSOR;
    int*       excl     = ws_i + OFF_EXCL;
    int*       bsum     = ws_i + OFF_BSUM;
    long long* cv       = (long long*)(ws_i + OFF_CV);
    float*     tx1      = ws_f + OFF_TX1;
    float*     tx2      = ws_f + OFF_TX2;

    // zero deg + cnt
    hipMemsetAsync(d_ws, 0, (size_t)(OFF_ROWSTART) * 4, stream);

    const int TB = 256;
    int eb = (E_EDGES + TB - 1) / TB;           // 3125
    int nb = (N_NODES + TB - 1) / TB;           // 196

    k_deg_cnt<<<eb, TB, 0, stream>>>(ei, ew, deg, cnt);
    k_dinv<<<nb, TB, 0, stream>>>(deg);
    k_scanA<<<nb, TB, 0, stream>>>(cnt, excl, bsum);
    k_scanB<<<1, TB, 0, stream>>>(bsum, nb);
    k_scanC<<<nb, TB, 0, stream>>>(excl, bsum, rowstart, cursor);
    k_scatter<<<eb, TB, 0, stream>>>(ei, ew, deg, cursor, cv);

    // Tx1 = L_hat @ X
    k_spmm<1, 0><<<(N_NODES + 3) / 4, TB, 0, stream>>>(rowstart, cv, X, X, tx1);
    // Tx2 = 2 * L_hat @ Tx1 - X
    k_spmm<2, 1><<<(N_NODES + 3) / 4, TB, 0, stream>>>(rowstart, cv, tx1, X, tx2);

    k_gru<<<(N_NODES + 63) / 64, TB, 0, stream>>>(X, tx1, tx2, Wxz, Wxh,
                                                  bxz, bhz, bxh, bhh, out);
}

// Round 3
// 261.688 us; speedup vs baseline: 1.4251x; 1.0468x over previous
//
#include <hip/hip_runtime.h>

// GConvGRU with H=0: only two ChebConvs on X survive.
//   Z  = sigmoid(X@Wz0 + Tx1@Wz1 + Tx2@Wz2 + b_xz + b_hz)
//   Ht = tanh   (X@Wh0 + Tx1@Wh1 + Tx2@Wh2 + b_xh + b_hh)
//   H_new = (1-Z)*Ht
// CSR build: sharded histograms + loc-fusion => scatter pass has no atomics.

#define N_NODES 50000
#define E_EDGES 800000
#define NC 64
#define NPAD 50176      // N rounded up
#define NSH 8           // histogram shards

// ws layout (4-byte element offsets). Build scratch aliases TX1 region.
#define OFF_ROWSTART 0          // int[50432]
#define OFF_CV       50432      // long long[800000] -> 1600000 elems
#define OFF_TX1      1650432    // float[3200000]
#define OFF_TX2      4850432    // float[3200000]
// aliased onto TX1 (only live before spmm1):
#define OFF_DEGS     1650432    // float[8*50176]
#define OFF_CNTS     2051840    // int[8*50176]  (counts -> shard prefixes in place)
#define OFF_DINV     2453248    // float[50176]
#define OFF_CNT      2503424    // int[50176]
#define OFF_EXCL     2553600    // int[50176]
#define OFF_BSUM     2603776    // int[256]
#define OFF_LOC      2604032    // int[800000] (loc | shard<<28)

// Pass 1: sharded degree + count, returning within-shard offsets (loc).
__global__ __launch_bounds__(256) void k_pass1(
        const int* __restrict__ ei, const float* __restrict__ ew,
        float* __restrict__ degS, int* __restrict__ cntS, int* __restrict__ loc) {
    int t = blockIdx.x * blockDim.x + threadIdx.x;
    if (t >= E_EDGES / 2) return;
    int e = t * 2;
    int sh = (blockIdx.x & (NSH - 1)) * NPAD;
    int2 s2 = *(const int2*)&ei[e];
    int2 d2 = *(const int2*)&ei[E_EDGES + e];
    float2 w2 = *(const float2*)&ew[e];

    atomicAdd(&degS[sh + s2.x], w2.x);
    atomicAdd(&degS[sh + s2.y], w2.y);
    int l0 = atomicAdd(&cntS[sh + d2.x], 1);
    int l1 = atomicAdd(&cntS[sh + d2.y], 1);
    int shb = (blockIdx.x & (NSH - 1)) << 28;
    *(int2*)&loc[e] = make_int2(l0 | shb, l1 | shb);
}

// Merge shards: dinv, per-node shard prefixes (in place), total count.
__global__ __launch_bounds__(256) void k_merge(
        float* __restrict__ degS, int* __restrict__ cntS,
        float* __restrict__ dinv, int* __restrict__ cnt) {
    int i = blockIdx.x * blockDim.x + threadIdx.x;
    if (i >= N_NODES) return;
    float dg = 0.f;
    int c[NSH];
    #pragma unroll
    for (int s = 0; s < NSH; ++s) {
        dg += degS[s * NPAD + i];
        c[s] = cntS[s * NPAD + i];
    }
    int tot = 0;
    #pragma unroll
    for (int s = 0; s < NSH; ++s) {
        cntS[s * NPAD + i] = tot;     // exclusive prefix across shards
        tot += c[s];
    }
    dinv[i] = dg > 0.f ? rsqrtf(dg) : 0.f;
    cnt[i] = tot;
}

__global__ void k_scanA(const int* __restrict__ cnt, int* __restrict__ excl,
                        int* __restrict__ bsum) {
    __shared__ int s[256];
    int tid = threadIdx.x;
    int i = blockIdx.x * 256 + tid;
    int v = (i < N_NODES) ? cnt[i] : 0;
    s[tid] = v; __syncthreads();
    for (int off = 1; off < 256; off <<= 1) {
        int t = (tid >= off) ? s[tid - off] : 0;
        __syncthreads();
        s[tid] += t;
        __syncthreads();
    }
    if (i < N_NODES) excl[i] = s[tid] - v;
    if (tid == 255) bsum[blockIdx.x] = s[255];
}

__global__ void k_scanB(int* __restrict__ bsum, int nb) {
    __shared__ int s[256];
    int tid = threadIdx.x;
    int v = (tid < nb) ? bsum[tid] : 0;
    s[tid] = v; __syncthreads();
    for (int off = 1; off < 256; off <<= 1) {
        int t = (tid >= off) ? s[tid - off] : 0;
        __syncthreads();
        s[tid] += t;
        __syncthreads();
    }
    if (tid < nb) bsum[tid] = s[tid] - v;
}

__global__ void k_scanC(const int* __restrict__ excl, const int* __restrict__ bsum,
                        int* __restrict__ row_start) {
    int i = blockIdx.x * 256 + threadIdx.x;
    if (i < N_NODES) row_start[i] = excl[i] + bsum[i >> 8];
    if (i == 0) row_start[N_NODES] = E_EDGES;
}

// Scatter with no atomics: pos = row_start[d] + shard_base[d] + loc.
__global__ __launch_bounds__(256) void k_scatter(
        const int* __restrict__ ei, const float* __restrict__ ew,
        const float* __restrict__ dinv, const int* __restrict__ row_start,
        const int* __restrict__ cntS, const int* __restrict__ loc,
        long long* __restrict__ cv) {
    int t = blockIdx.x * blockDim.x + threadIdx.x;
    if (t >= E_EDGES / 2) return;
    int e = t * 2;
    int2 s2 = *(const int2*)&ei[e];
    int2 d2 = *(const int2*)&ei[E_EDGES + e];
    float2 w2 = *(const float2*)&ew[e];
    int2 l2 = *(const int2*)&loc[e];

    {
        int sh = (l2.x >> 28) & (NSH - 1);
        int l = l2.x & 0x0fffffff;
        int pos = row_start[d2.x] + cntS[sh * NPAD + d2.x] + l;
        float wv = -w2.x * dinv[s2.x] * dinv[d2.x];
        cv[pos] = ((long long)__float_as_int(wv) << 32) | (unsigned int)s2.x;
    }
    {
        int sh = (l2.y >> 28) & (NSH - 1);
        int l = l2.y & 0x0fffffff;
        int pos = row_start[d2.y] + cntS[sh * NPAD + d2.y] + l;
        float wv = -w2.y * dinv[s2.y] * dinv[d2.y];
        cv[pos] = ((long long)__float_as_int(wv) << 32) | (unsigned int)s2.y;
    }
}

// Pull-mode SpMM: one wave per row, lane = channel.
template<int SCALE, int SUB>
__global__ __launch_bounds__(256) void k_spmm(
        const int* __restrict__ row_start, const long long* __restrict__ cv,
        const float* __restrict__ xin, const float* __restrict__ xprev,
        float* __restrict__ out) {
    int wid = (blockIdx.x << 2) + (threadIdx.x >> 6);
    int lane = threadIdx.x & 63;
    if (wid >= N_NODES) return;
    int start = row_start[wid];
    int end   = row_start[wid + 1];
    float acc = 0.f;
    #pragma unroll 4
    for (int j = start; j < end; ++j) {
        long long p = cv[j];
        int s = (int)(p & 0xffffffffLL);
        float wv = __int_as_float((int)(p >> 32));
        acc = fmaf(wv, xin[(size_t)s * NC + lane], acc);
    }
    float r = (float)SCALE * acc;
    if (SUB) r -= xprev[(size_t)wid * NC + lane];
    out[(size_t)wid * NC + lane] = r;
}

// Fused 3-term GEMM for both gates + GRU pointwise.
__global__ __launch_bounds__(256) void k_gru(
        const float* __restrict__ X, const float* __restrict__ Tx1,
        const float* __restrict__ Tx2,
        const float* __restrict__ Wxz, const float* __restrict__ Wxh,
        const float* __restrict__ bxz, const float* __restrict__ bhz,
        const float* __restrict__ bxh, const float* __restrict__ bhh,
        float* __restrict__ out) {
    __shared__ float sWz[64][64];    // [c][o]
    __shared__ float sWh[64][64];
    __shared__ float4 sIn[64][16];   // [node_local][c4]
    int tid = threadIdx.x;
    int o = tid & 63;
    int nq = tid >> 6;
    int node0 = blockIdx.x * 64;

    float accz[16], acch[16];
    #pragma unroll
    for (int i = 0; i < 16; ++i) { accz[i] = 0.f; acch[i] = 0.f; }

    const float* ins[3] = {X, Tx1, Tx2};
    #pragma unroll 1
    for (int k = 0; k < 3; ++k) {
        __syncthreads();
        #pragma unroll
        for (int r = 0; r < 16; ++r) {
            int idx = r * 256 + tid;
            ((float*)sWz)[idx] = Wxz[k * 4096 + idx];
            ((float*)sWh)[idx] = Wxh[k * 4096 + idx];
        }
        const float* ip = ins[k];
        #pragma unroll
        for (int r = 0; r < 4; ++r) {
            int fidx = r * 256 + tid;
            int node = fidx >> 4;
            int c4 = fidx & 15;
            int gn = node0 + node;
            float4 v = make_float4(0.f, 0.f, 0.f, 0.f);
            if (gn < N_NODES) v = *(const float4*)&ip[(size_t)gn * 64 + c4 * 4];
            sIn[node][c4] = v;
        }
        __syncthreads();
        #pragma unroll 4
        for (int c4 = 0; c4 < 16; ++c4) {
            float wz0 = sWz[c4 * 4 + 0][o];
            float wz1 = sWz[c4 * 4 + 1][o];
            float wz2 = sWz[c4 * 4 + 2][o];
            float wz3 = sWz[c4 * 4 + 3][o];
            float wh0 = sWh[c4 * 4 + 0][o];
            float wh1 = sWh[c4 * 4 + 1][o];
            float wh2 = sWh[c4 * 4 + 2][o];
            float wh3 = sWh[c4 * 4 + 3][o];
            #pragma unroll
            for (int nl = 0; nl < 16; ++nl) {
                float4 xv = sIn[nl * 4 + nq][c4];
                accz[nl] = fmaf(xv.x, wz0, accz[nl]);
                accz[nl] = fmaf(xv.y, wz1, accz[nl]);
                accz[nl] = fmaf(xv.z, wz2, accz[nl]);
                accz[nl] = fmaf(xv.w, wz3, accz[nl]);
                acch[nl] = fmaf(xv.x, wh0, acch[nl]);
                acch[nl] = fmaf(xv.y, wh1, acch[nl]);
                acch[nl] = fmaf(xv.z, wh2, acch[nl]);
                acch[nl] = fmaf(xv.w, wh3, acch[nl]);
            }
        }
    }

    float bz = bxz[o] + bhz[o];
    float bh = bxh[o] + bhh[o];
    #pragma unroll
    for (int nl = 0; nl < 16; ++nl) {
        int node = node0 + nl * 4 + nq;
        if (node < N_NODES) {
            float z = accz[nl] + bz;
            float h = acch[nl] + bh;
            float sig = 1.f / (1.f + __expf(-z));
            float e2 = __expf(-2.f * h);
            float th = (1.f - e2) / (1.f + e2);
            out[(size_t)node * 64 + o] = (1.f - sig) * th;
        }
    }
}

extern "C" void kernel_launch(void* const* d_in, const int* in_sizes, int n_in,
                              void* d_out, int out_size, void* d_ws, size_t ws_size,
                              hipStream_t stream) {
    const float* X   = (const float*)d_in[0];
    const int*   ei  = (const int*)d_in[1];
    const float* ew  = (const float*)d_in[2];
    const float* Wxz = (const float*)d_in[3];
    const float* Wxh = (const float*)d_in[7];
    const float* bxz = (const float*)d_in[9];
    const float* bhz = (const float*)d_in[10];
    const float* bxh = (const float*)d_in[13];
    const float* bhh = (const float*)d_in[14];
    float* out = (float*)d_out;

    float* ws_f = (float*)d_ws;
    int*   ws_i = (int*)d_ws;

    int*       rowstart = ws_i + OFF_ROWSTART;
    long long* cv       = (long long*)(ws_i + OFF_CV);
    float*     tx1      = ws_f + OFF_TX1;
    float*     tx2      = ws_f + OFF_TX2;
    float*     degS     = ws_f + OFF_DEGS;
    int*       cntS     = ws_i + OFF_CNTS;
    float*     dinv     = ws_f + OFF_DINV;
    int*       cnt      = ws_i + OFF_CNT;
    int*       excl     = ws_i + OFF_EXCL;
    int*       bsum     = ws_i + OFF_BSUM;
    int*       loc      = ws_i + OFF_LOC;

    // zero the sharded histograms (degS + cntS are contiguous)
    hipMemsetAsync((void*)degS, 0, (size_t)(2 * NSH * NPAD) * 4, stream);

    const int TB = 256;
    int pb = (E_EDGES / 2 + TB - 1) / TB;       // 1563 (pair-processing)
    int nb = (N_NODES + TB - 1) / TB;           // 196

    k_pass1<<<pb, TB, 0, stream>>>(ei, ew, degS, cntS, loc);
    k_merge<<<nb, TB, 0, stream>>>(degS, cntS, dinv, cnt);
    k_scanA<<<nb, TB, 0, stream>>>(cnt, excl, bsum);
    k_scanB<<<1, TB, 0, stream>>>(bsum, nb);
    k_scanC<<<nb, TB, 0, stream>>>(excl, bsum, rowstart);
    k_scatter<<<pb, TB, 0, stream>>>(ei, ew, dinv, rowstart, cntS, loc, cv);

    // Tx1 = L_hat @ X
    k_spmm<1, 0><<<(N_NODES + 3) / 4, TB, 0, stream>>>(rowstart, cv, X, X, tx1);
    // Tx2 = 2 * L_hat @ Tx1 - X
    k_spmm<2, 1><<<(N_NODES + 3) / 4, TB, 0, stream>>>(rowstart, cv, tx1, X, tx2);

    k_gru<<<(N_NODES + 63) / 64, TB, 0, stream>>>(X, tx1, tx2, Wxz, Wxh,
                                                  bxz, bhz, bxh, bhh, out);
}